// Round 1
// 321.572 us; speedup vs baseline: 1.0093x; 1.0093x over previous
//
#include <hip/hip_runtime.h>
#include <float.h>

#define NNODES 30000
#define NEDGES 480000
#define NFEATK 128
#define NH 16
#define NC 32
#define HC 512            // NH*NC
#define NCLASSES 10
#define NG 64
#define CAP 96            // padded per-node edge capacity (max deg ~45 for Poisson(16))

using half2v = __attribute__((ext_vector_type(2))) _Float16;
using half4 = __attribute__((ext_vector_type(4))) _Float16;
using half8 = __attribute__((ext_vector_type(8))) _Float16;
using f32x4 = __attribute__((ext_vector_type(4))) float;

// ---------------- merged prep: conversions + bucket init ----------------
// grid-stride over the largest range; all sub-tasks independent.
__global__ void prep0_kernel(const float* __restrict__ x, _Float16* __restrict__ xh,
                             const float* __restrict__ Wl1, const float* __restrict__ Wr1,
                             _Float16* __restrict__ Wlt1, _Float16* __restrict__ Wrt1,
                             const float* __restrict__ Wl2, const float* __restrict__ Wr2,
                             _Float16* __restrict__ Wlt2, _Float16* __restrict__ Wrt2,
                             int* __restrict__ cnt, int* __restrict__ csr) {
    int gtid = blockIdx.x * blockDim.x + threadIdx.x;
    int gstride = gridDim.x * blockDim.x;
    // x -> fp16 (float4-granular)
    for (int i = gtid; i < NNODES * NFEATK / 4; i += gstride) {
        float4 v = *(const float4*)&x[i * 4];
        half4 h = {(_Float16)v.x, (_Float16)v.y, (_Float16)v.z, (_Float16)v.w};
        *(half4*)&xh[i * 4] = h;
    }
    // W1 transposes (both l and r)
    for (int i = gtid; i < 2 * 512 * NFEATK; i += gstride) {
        int sel = i >= 512 * NFEATK;
        int idx = i - sel * 512 * NFEATK;
        const float* W = sel ? Wr1 : Wl1;
        _Float16* Wt = sel ? Wrt1 : Wlt1;
        int n = idx & 511, k = idx >> 9;
        Wt[n * NFEATK + k] = (_Float16)W[idx];
    }
    // W2 transposes
    for (int i = gtid; i < 2 * 512 * NC; i += gstride) {
        int sel = i >= 512 * NC;
        int idx = i - sel * 512 * NC;
        const float* W = sel ? Wr2 : Wl2;
        _Float16* Wt = sel ? Wrt2 : Wlt2;
        int n = idx & 511, k = idx >> 9;
        Wt[n * NC + k] = (_Float16)W[idx];
    }
    // bucket init: self-loop in slot 0, cnt = 1
    for (int i = gtid; i < NNODES; i += gstride) {
        cnt[i] = 1;
        csr[i * CAP] = i;
    }
}

// ---------------- bucket scatter: one atomic pass, no count/scan ----------------
__global__ void scatter_kernel(const int* __restrict__ src, const int* __restrict__ dst,
                               int* __restrict__ cnt, int* __restrict__ csr) {
    int e = blockIdx.x * blockDim.x + threadIdx.x;
    if (e >= NEDGES) return;
    int s = src[e], d = dst[e];
    int pos = atomicAdd(&cnt[d], 1);
    csr[d * CAP + pos] = s;
}

// ---------------- dual MFMA GEMM (unchanged) ----------------
template <int K>
__launch_bounds__(256)
__global__ void dual_gemm_kernel(const _Float16* __restrict__ A,
                                 const _Float16* __restrict__ Wlt, const _Float16* __restrict__ Wrt,
                                 const float* __restrict__ bl, const float* __restrict__ br,
                                 _Float16* __restrict__ Yl, _Float16* __restrict__ Yr) {
    constexpr int Kc = K / 8;
    constexpr int AH = 64 * K;
    constexpr int BH = 128 * K;
    constexpr int YSH = 64 * 136;
    constexpr int SMEMH = (AH + BH > YSH) ? (AH + BH) : YSH;
    __shared__ __align__(16) _Float16 smem[SMEMH];
    _Float16* as = smem;
    _Float16* bs = smem + AH;

    int tid = threadIdx.x;
    int sel = blockIdx.y >> 2;
    int nbase = (blockIdx.y & 3) * 128;
    const _Float16* Bt = sel ? Wrt : Wlt;
    const float* bias = sel ? br : bl;
    _Float16* Y = sel ? Yr : Yl;
    int mb = blockIdx.x;

    for (int c = tid; c < 64 * Kc; c += 256) {
        int row = c / Kc, k8 = c % Kc;
        int arow = mb * 64 + row; if (arow > NNODES - 1) arow = NNODES - 1;
        half8 v = *(const half8*)&A[(size_t)arow * K + k8 * 8];
        *(half8*)&as[(row * Kc + (k8 ^ (row & (Kc - 1)))) * 8] = v;
    }
    for (int c = tid; c < 128 * Kc; c += 256) {
        int row = c / Kc, k8 = c % Kc;
        half8 v = *(const half8*)&Bt[(size_t)(nbase + row) * K + k8 * 8];
        *(half8*)&bs[(row * Kc + (k8 ^ (row & (Kc - 1)))) * 8] = v;
    }
    __syncthreads();

    int wave = tid >> 6, lane = tid & 63;
    int quad = lane >> 4, l16 = lane & 15;
    int am = l16 & (Kc - 1);

    f32x4 acc[8];
    #pragma unroll
    for (int f = 0; f < 8; f++) acc[f] = (f32x4){0.f, 0.f, 0.f, 0.f};

    #pragma unroll
    for (int kk = 0; kk < Kc; kk += 4) {
        int k8 = (kk + quad) ^ am;
        half8 a = *(const half8*)&as[((wave * 16 + l16) * Kc + k8) * 8];
        #pragma unroll
        for (int f = 0; f < 8; f++) {
            half8 b = *(const half8*)&bs[((f * 16 + l16) * Kc + k8) * 8];
            acc[f] = __builtin_amdgcn_mfma_f32_16x16x32_f16(a, b, acc[f], 0, 0, 0);
        }
    }
    __syncthreads();

    _Float16* ys = smem;
    #pragma unroll
    for (int f = 0; f < 8; f++) {
        float bv = bias[nbase + f * 16 + l16];
        #pragma unroll
        for (int r = 0; r < 4; r++) {
            ys[(wave * 16 + quad * 4 + r) * 136 + f * 16 + l16] = (_Float16)(acc[f][r] + bv);
        }
    }
    __syncthreads();
    int mtop = mb * 64;
    for (int c = tid; c < 64 * 16; c += 256) {
        int r = c >> 4, cc = (c & 15) * 8;
        int grow = mtop + r;
        if (grow < NNODES)
            *(half8*)&Y[(size_t)grow * HC + nbase + cc] = *(half8*)&ys[r * 136 + cc];
    }
}

// ---------------- fused GATv2 edge stage: packed-f16 score, 64thr x 8ch ----------------
__device__ inline half2v lrelu2(half2v e) {
    // leaky(e) = max(e, 0.2*e) since slope 0.2 in (0,1)
    half2v s = e * half2v{(_Float16)0.2f, (_Float16)0.2f};
    return __builtin_elementwise_max(e, s);
}

#if __has_builtin(__builtin_amdgcn_fdot2)
#define FDOT2(a, b, c) __builtin_amdgcn_fdot2((a), (b), (c), false)
#else
__device__ inline float fdot2_sw(half2v a, half2v b, float c) {
    half2v p = a * b;
    return c + (float)p.x + (float)p.y;
}
#define FDOT2(a, b, c) fdot2_sw((a), (b), (c))
#endif

template <typename OUT>
__launch_bounds__(64)
__global__ void gat_edge_kernel(const _Float16* __restrict__ xlh, const _Float16* __restrict__ xrh,
                                const float* __restrict__ att, const float* __restrict__ bvec,
                                const int* __restrict__ cnt, const int* __restrict__ csr_src,
                                OUT* __restrict__ hout) {
    int d = blockIdx.x;
    int t = threadIdx.x;          // 64 threads x 8 channels = 512
    int col = t * 8;              // head = t/4, 4 lanes per head

    half8 xrq = *(const half8*)&xrh[(size_t)d * HC + col];
    half2v xr0 = {xrq[0], xrq[1]}, xr1 = {xrq[2], xrq[3]};
    half2v xr2 = {xrq[4], xrq[5]}, xr3 = {xrq[6], xrq[7]};
    float4 atta = *(const float4*)&att[col];
    float4 attb = *(const float4*)&att[col + 4];
    half2v at0 = {(_Float16)atta.x, (_Float16)atta.y};
    half2v at1 = {(_Float16)atta.z, (_Float16)atta.w};
    half2v at2 = {(_Float16)attb.x, (_Float16)attb.y};
    half2v at3 = {(_Float16)attb.z, (_Float16)attb.w};

    int beg = d * CAP, end = beg + cnt[d];

    float l = 0.f;
    float a[8];
    #pragma unroll
    for (int c = 0; c < 8; c++) a[c] = 0.f;

    for (int i = beg; i < end; i += 4) {
        int n = end - i;
        int s0 = csr_src[i];
        int s1 = csr_src[n > 1 ? i + 1 : i];
        int s2 = csr_src[n > 2 ? i + 2 : i];
        int s3 = csr_src[n > 3 ? i + 3 : i];
        half8 q0 = *(const half8*)&xlh[(size_t)s0 * HC + col];
        half8 q1 = *(const half8*)&xlh[(size_t)s1 * HC + col];
        half8 q2 = *(const half8*)&xlh[(size_t)s2 * HC + col];
        half8 q3 = *(const half8*)&xlh[(size_t)s3 * HC + col];

        // packed-f16 score: e = leaky(xl+xr); v += dot2(e, att)  (f32 accumulate)
        float v0 = 0.f, v1 = 0.f, v2 = 0.f, v3 = 0.f;
        v0 = FDOT2(lrelu2(half2v{q0[0], q0[1]} + xr0), at0, v0);
        v0 = FDOT2(lrelu2(half2v{q0[2], q0[3]} + xr1), at1, v0);
        v0 = FDOT2(lrelu2(half2v{q0[4], q0[5]} + xr2), at2, v0);
        v0 = FDOT2(lrelu2(half2v{q0[6], q0[7]} + xr3), at3, v0);
        v1 = FDOT2(lrelu2(half2v{q1[0], q1[1]} + xr0), at0, v1);
        v1 = FDOT2(lrelu2(half2v{q1[2], q1[3]} + xr1), at1, v1);
        v1 = FDOT2(lrelu2(half2v{q1[4], q1[5]} + xr2), at2, v1);
        v1 = FDOT2(lrelu2(half2v{q1[6], q1[7]} + xr3), at3, v1);
        v2 = FDOT2(lrelu2(half2v{q2[0], q2[1]} + xr0), at0, v2);
        v2 = FDOT2(lrelu2(half2v{q2[2], q2[3]} + xr1), at1, v2);
        v2 = FDOT2(lrelu2(half2v{q2[4], q2[5]} + xr2), at2, v2);
        v2 = FDOT2(lrelu2(half2v{q2[6], q2[7]} + xr3), at3, v2);
        v3 = FDOT2(lrelu2(half2v{q3[0], q3[1]} + xr0), at0, v3);
        v3 = FDOT2(lrelu2(half2v{q3[2], q3[3]} + xr1), at1, v3);
        v3 = FDOT2(lrelu2(half2v{q3[4], q3[5]} + xr2), at2, v3);
        v3 = FDOT2(lrelu2(half2v{q3[6], q3[7]} + xr3), at3, v3);

        // head reduce: 4 lanes per head -> 2 butterfly levels
        v0 += __shfl_xor(v0, 1); v1 += __shfl_xor(v1, 1);
        v2 += __shfl_xor(v2, 1); v3 += __shfl_xor(v3, 1);
        v0 += __shfl_xor(v0, 2); v1 += __shfl_xor(v1, 2);
        v2 += __shfl_xor(v2, 2); v3 += __shfl_xor(v3, 2);

        float p0 = __expf(v0);
        float p1 = (n > 1) ? __expf(v1) : 0.f;
        float p2 = (n > 2) ? __expf(v2) : 0.f;
        float p3 = (n > 3) ? __expf(v3) : 0.f;
        l += (p0 + p1) + (p2 + p3);

        // aggregation: f32 accumulate, f16 operand -> v_fma_mix
        #pragma unroll
        for (int c = 0; c < 8; c++) {
            a[c] += p0 * (float)q0[c];
            a[c] += p1 * (float)q1[c];
            a[c] += p2 * (float)q2[c];
            a[c] += p3 * (float)q3[c];
        }
    }

    float inv = 1.0f / l;

    __shared__ float red[512];
    #pragma unroll
    for (int c = 0; c < 8; c++) red[col + c] = a[c] * inv;
    __syncthreads();
    if (t < 32) {
        float ssum = 0.f;
        #pragma unroll
        for (int hh = 0; hh < NH; ++hh) ssum += red[hh * 32 + t];
        float r = ssum * (1.0f / (float)NH) + bvec[t];
        r = (r > 0.f) ? r : 0.01f * r;
        hout[d * NC + t] = (OUT)r;
    }
}

// ---------------- fused pool + classifier (unchanged) ----------------
__launch_bounds__(1024)
__global__ void pool_classify_kernel(const float* __restrict__ h, const int* __restrict__ batch,
                                     const float* __restrict__ Wc, const float* __restrict__ bc,
                                     float* __restrict__ out) {
    int g = blockIdx.x;
    int lo = 0, hi = NNODES;
    while (lo < hi) { int mid = (lo + hi) >> 1; if (batch[mid] < g) lo = mid + 1; else hi = mid; }
    int start = lo;
    hi = NNODES;
    while (lo < hi) { int mid = (lo + hi) >> 1; if (batch[mid] <= g) lo = mid + 1; else hi = mid; }
    int endn = lo;
    int cntg = endn - start;

    int tid = threadIdx.x;
    int c = tid & 31, nl = tid >> 5;              // 32 node-lanes x 32 channels
    float s = 0.f;
    for (int n = start + nl; n < endn; n += 32) s += h[n * NC + c];
    __shared__ float red[1024];
    red[tid] = s;
    __syncthreads();
    if (tid < 32) {
        float t = 0.f;
        #pragma unroll
        for (int j = 0; j < 32; j++) t += red[j * 32 + tid];
        red[tid] = t / fmaxf((float)cntg, 1.0f);
    }
    __syncthreads();
    if (tid < NCLASSES) {
        float sum = bc[tid];
        #pragma unroll
        for (int cc = 0; cc < NC; cc++) sum += red[cc] * Wc[cc * NCLASSES + tid];
        out[g * NCLASSES + tid] = sum;
    }
}

// ---------------- launch ----------------

extern "C" void kernel_launch(void* const* d_in, const int* in_sizes, int n_in,
                              void* d_out, int out_size, void* d_ws, size_t ws_size,
                              hipStream_t stream) {
    const float* x    = (const float*)d_in[0];
    const float* Wl1  = (const float*)d_in[1];
    const float* bl1  = (const float*)d_in[2];
    const float* Wr1  = (const float*)d_in[3];
    const float* br1  = (const float*)d_in[4];
    const float* att1 = (const float*)d_in[5];
    const float* b1   = (const float*)d_in[6];
    const float* Wl2  = (const float*)d_in[7];
    const float* bl2  = (const float*)d_in[8];
    const float* Wr2  = (const float*)d_in[9];
    const float* br2  = (const float*)d_in[10];
    const float* att2 = (const float*)d_in[11];
    const float* b2   = (const float*)d_in[12];
    const float* Wc   = (const float*)d_in[13];
    const float* bc   = (const float*)d_in[14];
    const int* ei     = (const int*)d_in[15];
    const int* batch  = (const int*)d_in[16];
    float* out = (float*)d_out;

    const int* srcp = ei;
    const int* dstp = ei + NEDGES;

    char* ws = (char*)d_ws;
    size_t off = 0;
    auto alloc = [&](size_t bytes) -> void* {
        void* p = ws + off;
        off += (bytes + 255) & ~(size_t)255;
        return p;
    };
    _Float16* xlh  = (_Float16*)alloc(sizeof(_Float16) * (size_t)NNODES * HC);
    _Float16* xrh  = (_Float16*)alloc(sizeof(_Float16) * (size_t)NNODES * HC);
    _Float16* xh   = (_Float16*)alloc(sizeof(_Float16) * (size_t)NNODES * NFEATK);
    _Float16* h1   = (_Float16*)alloc(sizeof(_Float16) * (size_t)NNODES * NC);
    float* h2      = (float*)alloc(sizeof(float) * (size_t)NNODES * NC);
    _Float16* Wlt1 = (_Float16*)alloc(sizeof(_Float16) * 512 * NFEATK);
    _Float16* Wrt1 = (_Float16*)alloc(sizeof(_Float16) * 512 * NFEATK);
    _Float16* Wlt2 = (_Float16*)alloc(sizeof(_Float16) * 512 * NC);
    _Float16* Wrt2 = (_Float16*)alloc(sizeof(_Float16) * 512 * NC);
    int*   cnt     = (int*)alloc(sizeof(int) * NNODES);
    int*   csr     = (int*)alloc(sizeof(int) * (size_t)NNODES * CAP);

    // prep: conversions + bucket init (one dispatch)
    prep0_kernel<<<512, 256, 0, stream>>>(x, xh, Wl1, Wr1, Wlt1, Wrt1,
                                          Wl2, Wr2, Wlt2, Wrt2, cnt, csr);
    // bucket scatter (one atomic pass; no count/scan)
    scatter_kernel<<<(NEDGES + 255) / 256, 256, 0, stream>>>(srcp, dstp, cnt, csr);

    const int MB = (NNODES + 63) / 64;   // 469

    // Layer 1
    dual_gemm_kernel<NFEATK><<<dim3(MB, 8), 256, 0, stream>>>(xh, Wlt1, Wrt1, bl1, br1, xlh, xrh);
    gat_edge_kernel<_Float16><<<NNODES, 64, 0, stream>>>(xlh, xrh, att1, b1, cnt, csr, h1);

    // Layer 2
    dual_gemm_kernel<NC><<<dim3(MB, 8), 256, 0, stream>>>(h1, Wlt2, Wrt2, bl2, br2, xlh, xrh);
    gat_edge_kernel<float><<<NNODES, 64, 0, stream>>>(xlh, xrh, att2, b2, cnt, csr, h2);

    // Pool + classify
    pool_classify_kernel<<<NG, 1024, 0, stream>>>(h2, batch, Wc, bc, out);
}

// Round 2
// 320.977 us; speedup vs baseline: 1.0111x; 1.0019x over previous
//
#include <hip/hip_runtime.h>
#include <float.h>

#define NNODES 30000
#define NEDGES 480000
#define NFEATK 128
#define NH 16
#define NC 32
#define HC 512            // NH*NC
#define NCLASSES 10
#define NG 64
#define CAP 96            // padded per-node edge capacity (max deg ~45 for Poisson(16))

using half2v = __attribute__((ext_vector_type(2))) _Float16;
using half4 = __attribute__((ext_vector_type(4))) _Float16;
using half8 = __attribute__((ext_vector_type(8))) _Float16;
using f32x4 = __attribute__((ext_vector_type(4))) float;

// ---------------- merged prep: conversions + bucket init ----------------
__global__ void prep0_kernel(const float* __restrict__ x, _Float16* __restrict__ xh,
                             const float* __restrict__ Wl1, const float* __restrict__ Wr1,
                             _Float16* __restrict__ Wlt1, _Float16* __restrict__ Wrt1,
                             const float* __restrict__ Wl2, const float* __restrict__ Wr2,
                             _Float16* __restrict__ Wlt2, _Float16* __restrict__ Wrt2,
                             int* __restrict__ cnt, int* __restrict__ csr) {
    int gtid = blockIdx.x * blockDim.x + threadIdx.x;
    int gstride = gridDim.x * blockDim.x;
    // x -> fp16 (float4-granular)
    for (int i = gtid; i < NNODES * NFEATK / 4; i += gstride) {
        float4 v = *(const float4*)&x[i * 4];
        half4 h = {(_Float16)v.x, (_Float16)v.y, (_Float16)v.z, (_Float16)v.w};
        *(half4*)&xh[i * 4] = h;
    }
    // W1 transposes (both l and r)
    for (int i = gtid; i < 2 * 512 * NFEATK; i += gstride) {
        int sel = i >= 512 * NFEATK;
        int idx = i - sel * 512 * NFEATK;
        const float* W = sel ? Wr1 : Wl1;
        _Float16* Wt = sel ? Wrt1 : Wlt1;
        int n = idx & 511, k = idx >> 9;
        Wt[n * NFEATK + k] = (_Float16)W[idx];
    }
    // W2 transposes
    for (int i = gtid; i < 2 * 512 * NC; i += gstride) {
        int sel = i >= 512 * NC;
        int idx = i - sel * 512 * NC;
        const float* W = sel ? Wr2 : Wl2;
        _Float16* Wt = sel ? Wrt2 : Wlt2;
        int n = idx & 511, k = idx >> 9;
        Wt[n * NC + k] = (_Float16)W[idx];
    }
    // bucket init: self-loop in slot 0, cnt = 1
    for (int i = gtid; i < NNODES; i += gstride) {
        cnt[i] = 1;
        csr[i * CAP] = i;
    }
}

// ---------------- bucket scatter: one atomic pass, no count/scan ----------------
__global__ void scatter_kernel(const int* __restrict__ src, const int* __restrict__ dst,
                               int* __restrict__ cnt, int* __restrict__ csr) {
    int e = blockIdx.x * blockDim.x + threadIdx.x;
    if (e >= NEDGES) return;
    int s = src[e], d = dst[e];
    int pos = atomicAdd(&cnt[d], 1);
    csr[d * CAP + pos] = s;
}

// ---------------- dual MFMA GEMM (unchanged) ----------------
template <int K>
__launch_bounds__(256)
__global__ void dual_gemm_kernel(const _Float16* __restrict__ A,
                                 const _Float16* __restrict__ Wlt, const _Float16* __restrict__ Wrt,
                                 const float* __restrict__ bl, const float* __restrict__ br,
                                 _Float16* __restrict__ Yl, _Float16* __restrict__ Yr) {
    constexpr int Kc = K / 8;
    constexpr int AH = 64 * K;
    constexpr int BH = 128 * K;
    constexpr int YSH = 64 * 136;
    constexpr int SMEMH = (AH + BH > YSH) ? (AH + BH) : YSH;
    __shared__ __align__(16) _Float16 smem[SMEMH];
    _Float16* as = smem;
    _Float16* bs = smem + AH;

    int tid = threadIdx.x;
    int sel = blockIdx.y >> 2;
    int nbase = (blockIdx.y & 3) * 128;
    const _Float16* Bt = sel ? Wrt : Wlt;
    const float* bias = sel ? br : bl;
    _Float16* Y = sel ? Yr : Yl;
    int mb = blockIdx.x;

    for (int c = tid; c < 64 * Kc; c += 256) {
        int row = c / Kc, k8 = c % Kc;
        int arow = mb * 64 + row; if (arow > NNODES - 1) arow = NNODES - 1;
        half8 v = *(const half8*)&A[(size_t)arow * K + k8 * 8];
        *(half8*)&as[(row * Kc + (k8 ^ (row & (Kc - 1)))) * 8] = v;
    }
    for (int c = tid; c < 128 * Kc; c += 256) {
        int row = c / Kc, k8 = c % Kc;
        half8 v = *(const half8*)&Bt[(size_t)(nbase + row) * K + k8 * 8];
        *(half8*)&bs[(row * Kc + (k8 ^ (row & (Kc - 1)))) * 8] = v;
    }
    __syncthreads();

    int wave = tid >> 6, lane = tid & 63;
    int quad = lane >> 4, l16 = lane & 15;
    int am = l16 & (Kc - 1);

    f32x4 acc[8];
    #pragma unroll
    for (int f = 0; f < 8; f++) acc[f] = (f32x4){0.f, 0.f, 0.f, 0.f};

    #pragma unroll
    for (int kk = 0; kk < Kc; kk += 4) {
        int k8 = (kk + quad) ^ am;
        half8 a = *(const half8*)&as[((wave * 16 + l16) * Kc + k8) * 8];
        #pragma unroll
        for (int f = 0; f < 8; f++) {
            half8 b = *(const half8*)&bs[((f * 16 + l16) * Kc + k8) * 8];
            acc[f] = __builtin_amdgcn_mfma_f32_16x16x32_f16(a, b, acc[f], 0, 0, 0);
        }
    }
    __syncthreads();

    _Float16* ys = smem;
    #pragma unroll
    for (int f = 0; f < 8; f++) {
        float bv = bias[nbase + f * 16 + l16];
        #pragma unroll
        for (int r = 0; r < 4; r++) {
            ys[(wave * 16 + quad * 4 + r) * 136 + f * 16 + l16] = (_Float16)(acc[f][r] + bv);
        }
    }
    __syncthreads();
    int mtop = mb * 64;
    for (int c = tid; c < 64 * 16; c += 256) {
        int r = c >> 4, cc = (c & 15) * 8;
        int grow = mtop + r;
        if (grow < NNODES)
            *(half8*)&Y[(size_t)grow * HC + nbase + cc] = *(half8*)&ys[r * 136 + cc];
    }
}

// ---------------- fused GATv2 edge stage: 4 nodes/block, 1 wave/node ----------------
__device__ inline half2v lrelu2(half2v e) {
    // leaky(e) = max(e, 0.2*e) since slope 0.2 in (0,1)
    half2v s = e * half2v{(_Float16)0.2f, (_Float16)0.2f};
    return __builtin_elementwise_max(e, s);
}

#if __has_builtin(__builtin_amdgcn_fdot2)
#define FDOT2(a, b, c) __builtin_amdgcn_fdot2((a), (b), (c), false)
#else
__device__ inline float fdot2_sw(half2v a, half2v b, float c) {
    half2v p = a * b;
    return c + (float)p.x + (float)p.y;
}
#define FDOT2(a, b, c) fdot2_sw((a), (b), (c))
#endif

template <typename OUT>
__launch_bounds__(256)
__global__ void gat_edge_kernel(const _Float16* __restrict__ xlh, const _Float16* __restrict__ xrh,
                                const float* __restrict__ att, const float* __restrict__ bvec,
                                const int* __restrict__ cnt, const int* __restrict__ csr_src,
                                OUT* __restrict__ hout) {
    int wv = threadIdx.x >> 6;           // wave in block -> node slot
    int t = threadIdx.x & 63;            // lane in wave
    int d = blockIdx.x * 4 + wv;         // dst node (NNODES % 4 == 0)
    int col = t * 8;                     // head = t/4, 4 lanes per head

    half8 xrq = *(const half8*)&xrh[(size_t)d * HC + col];
    half2v xr0 = {xrq[0], xrq[1]}, xr1 = {xrq[2], xrq[3]};
    half2v xr2 = {xrq[4], xrq[5]}, xr3 = {xrq[6], xrq[7]};
    float4 atta = *(const float4*)&att[col];
    float4 attb = *(const float4*)&att[col + 4];
    half2v at0 = {(_Float16)atta.x, (_Float16)atta.y};
    half2v at1 = {(_Float16)atta.z, (_Float16)atta.w};
    half2v at2 = {(_Float16)attb.x, (_Float16)attb.y};
    half2v at3 = {(_Float16)attb.z, (_Float16)attb.w};

    int beg = d * CAP, end = beg + cnt[d];

    float l = 0.f;
    float a[8];
    #pragma unroll
    for (int c = 0; c < 8; c++) a[c] = 0.f;

    for (int i = beg; i < end; i += 4) {
        int n = end - i;
        int s0 = csr_src[i];
        int s1 = csr_src[n > 1 ? i + 1 : i];
        int s2 = csr_src[n > 2 ? i + 2 : i];
        int s3 = csr_src[n > 3 ? i + 3 : i];
        half8 q0 = *(const half8*)&xlh[(size_t)s0 * HC + col];
        half8 q1 = *(const half8*)&xlh[(size_t)s1 * HC + col];
        half8 q2 = *(const half8*)&xlh[(size_t)s2 * HC + col];
        half8 q3 = *(const half8*)&xlh[(size_t)s3 * HC + col];

        // packed-f16 score: e = leaky(xl+xr); v += dot2(e, att)  (f32 accumulate)
        float v0 = 0.f, v1 = 0.f, v2 = 0.f, v3 = 0.f;
        v0 = FDOT2(lrelu2(half2v{q0[0], q0[1]} + xr0), at0, v0);
        v0 = FDOT2(lrelu2(half2v{q0[2], q0[3]} + xr1), at1, v0);
        v0 = FDOT2(lrelu2(half2v{q0[4], q0[5]} + xr2), at2, v0);
        v0 = FDOT2(lrelu2(half2v{q0[6], q0[7]} + xr3), at3, v0);
        v1 = FDOT2(lrelu2(half2v{q1[0], q1[1]} + xr0), at0, v1);
        v1 = FDOT2(lrelu2(half2v{q1[2], q1[3]} + xr1), at1, v1);
        v1 = FDOT2(lrelu2(half2v{q1[4], q1[5]} + xr2), at2, v1);
        v1 = FDOT2(lrelu2(half2v{q1[6], q1[7]} + xr3), at3, v1);
        v2 = FDOT2(lrelu2(half2v{q2[0], q2[1]} + xr0), at0, v2);
        v2 = FDOT2(lrelu2(half2v{q2[2], q2[3]} + xr1), at1, v2);
        v2 = FDOT2(lrelu2(half2v{q2[4], q2[5]} + xr2), at2, v2);
        v2 = FDOT2(lrelu2(half2v{q2[6], q2[7]} + xr3), at3, v2);
        v3 = FDOT2(lrelu2(half2v{q3[0], q3[1]} + xr0), at0, v3);
        v3 = FDOT2(lrelu2(half2v{q3[2], q3[3]} + xr1), at1, v3);
        v3 = FDOT2(lrelu2(half2v{q3[4], q3[5]} + xr2), at2, v3);
        v3 = FDOT2(lrelu2(half2v{q3[6], q3[7]} + xr3), at3, v3);

        // head reduce: 4 lanes per head -> 2 butterfly levels
        v0 += __shfl_xor(v0, 1); v1 += __shfl_xor(v1, 1);
        v2 += __shfl_xor(v2, 1); v3 += __shfl_xor(v3, 1);
        v0 += __shfl_xor(v0, 2); v1 += __shfl_xor(v1, 2);
        v2 += __shfl_xor(v2, 2); v3 += __shfl_xor(v3, 2);

        float p0 = __expf(v0);
        float p1 = (n > 1) ? __expf(v1) : 0.f;
        float p2 = (n > 2) ? __expf(v2) : 0.f;
        float p3 = (n > 3) ? __expf(v3) : 0.f;
        l += (p0 + p1) + (p2 + p3);

        // aggregation: f32 accumulate, f16 operand -> v_fma_mix
        #pragma unroll
        for (int c = 0; c < 8; c++) {
            a[c] += p0 * (float)q0[c];
            a[c] += p1 * (float)q1[c];
            a[c] += p2 * (float)q2[c];
            a[c] += p3 * (float)q3[c];
        }
    }

    // normalize per (node, head) BEFORE head-mean: l is uniform within a
    // 4-lane head group, distinct across heads.
    float inv = 1.0f / l;
    #pragma unroll
    for (int c = 0; c < 8; c++) a[c] *= inv;

    // head-mean in-register: sum over the 16 lanes with equal (t & 3)
    // (those hold the same 8 channels-in-head across the 16 heads).
    #pragma unroll
    for (int off = 4; off < 64; off <<= 1) {
        #pragma unroll
        for (int c = 0; c < 8; c++) a[c] += __shfl_xor(a[c], off);
    }

    if (t < 4) {
        #pragma unroll
        for (int c = 0; c < 8; c++) {
            float r = a[c] * (1.0f / (float)NH) + bvec[t * 8 + c];
            r = (r > 0.f) ? r : 0.01f * r;
            hout[(size_t)d * NC + t * 8 + c] = (OUT)r;
        }
    }
}

// ---------------- fused pool + classifier (unchanged) ----------------
__launch_bounds__(1024)
__global__ void pool_classify_kernel(const float* __restrict__ h, const int* __restrict__ batch,
                                     const float* __restrict__ Wc, const float* __restrict__ bc,
                                     float* __restrict__ out) {
    int g = blockIdx.x;
    int lo = 0, hi = NNODES;
    while (lo < hi) { int mid = (lo + hi) >> 1; if (batch[mid] < g) lo = mid + 1; else hi = mid; }
    int start = lo;
    hi = NNODES;
    while (lo < hi) { int mid = (lo + hi) >> 1; if (batch[mid] <= g) lo = mid + 1; else hi = mid; }
    int endn = lo;
    int cntg = endn - start;

    int tid = threadIdx.x;
    int c = tid & 31, nl = tid >> 5;              // 32 node-lanes x 32 channels
    float s = 0.f;
    for (int n = start + nl; n < endn; n += 32) s += h[n * NC + c];
    __shared__ float red[1024];
    red[tid] = s;
    __syncthreads();
    if (tid < 32) {
        float t = 0.f;
        #pragma unroll
        for (int j = 0; j < 32; j++) t += red[j * 32 + tid];
        red[tid] = t / fmaxf((float)cntg, 1.0f);
    }
    __syncthreads();
    if (tid < NCLASSES) {
        float sum = bc[tid];
        #pragma unroll
        for (int cc = 0; cc < NC; cc++) sum += red[cc] * Wc[cc * NCLASSES + tid];
        out[g * NCLASSES + tid] = sum;
    }
}

// ---------------- launch ----------------

extern "C" void kernel_launch(void* const* d_in, const int* in_sizes, int n_in,
                              void* d_out, int out_size, void* d_ws, size_t ws_size,
                              hipStream_t stream) {
    const float* x    = (const float*)d_in[0];
    const float* Wl1  = (const float*)d_in[1];
    const float* bl1  = (const float*)d_in[2];
    const float* Wr1  = (const float*)d_in[3];
    const float* br1  = (const float*)d_in[4];
    const float* att1 = (const float*)d_in[5];
    const float* b1   = (const float*)d_in[6];
    const float* Wl2  = (const float*)d_in[7];
    const float* bl2  = (const float*)d_in[8];
    const float* Wr2  = (const float*)d_in[9];
    const float* br2  = (const float*)d_in[10];
    const float* att2 = (const float*)d_in[11];
    const float* b2   = (const float*)d_in[12];
    const float* Wc   = (const float*)d_in[13];
    const float* bc   = (const float*)d_in[14];
    const int* ei     = (const int*)d_in[15];
    const int* batch  = (const int*)d_in[16];
    float* out = (float*)d_out;

    const int* srcp = ei;
    const int* dstp = ei + NEDGES;

    char* ws = (char*)d_ws;
    size_t off = 0;
    auto alloc = [&](size_t bytes) -> void* {
        void* p = ws + off;
        off += (bytes + 255) & ~(size_t)255;
        return p;
    };
    _Float16* xlh  = (_Float16*)alloc(sizeof(_Float16) * (size_t)NNODES * HC);
    _Float16* xrh  = (_Float16*)alloc(sizeof(_Float16) * (size_t)NNODES * HC);
    _Float16* xh   = (_Float16*)alloc(sizeof(_Float16) * (size_t)NNODES * NFEATK);
    _Float16* h1   = (_Float16*)alloc(sizeof(_Float16) * (size_t)NNODES * NC);
    float* h2      = (float*)alloc(sizeof(float) * (size_t)NNODES * NC);
    _Float16* Wlt1 = (_Float16*)alloc(sizeof(_Float16) * 512 * NFEATK);
    _Float16* Wrt1 = (_Float16*)alloc(sizeof(_Float16) * 512 * NFEATK);
    _Float16* Wlt2 = (_Float16*)alloc(sizeof(_Float16) * 512 * NC);
    _Float16* Wrt2 = (_Float16*)alloc(sizeof(_Float16) * 512 * NC);
    int*   cnt     = (int*)alloc(sizeof(int) * NNODES);
    int*   csr     = (int*)alloc(sizeof(int) * (size_t)NNODES * CAP);

    // prep: conversions + bucket init (one dispatch)
    prep0_kernel<<<512, 256, 0, stream>>>(x, xh, Wl1, Wr1, Wlt1, Wrt1,
                                          Wl2, Wr2, Wlt2, Wrt2, cnt, csr);
    // bucket scatter (one atomic pass; no count/scan)
    scatter_kernel<<<(NEDGES + 255) / 256, 256, 0, stream>>>(srcp, dstp, cnt, csr);

    const int MB = (NNODES + 63) / 64;   // 469

    // Layer 1
    dual_gemm_kernel<NFEATK><<<dim3(MB, 8), 256, 0, stream>>>(xh, Wlt1, Wrt1, bl1, br1, xlh, xrh);
    gat_edge_kernel<_Float16><<<NNODES / 4, 256, 0, stream>>>(xlh, xrh, att1, b1, cnt, csr, h1);

    // Layer 2
    dual_gemm_kernel<NC><<<dim3(MB, 8), 256, 0, stream>>>(h1, Wlt2, Wrt2, bl2, br2, xlh, xrh);
    gat_edge_kernel<float><<<NNODES / 4, 256, 0, stream>>>(xlh, xrh, att2, b2, cnt, csr, h2);

    // Pool + classify
    pool_classify_kernel<<<NG, 1024, 0, stream>>>(h2, batch, Wc, bc, out);
}